// Round 4
// baseline (369.442 us; speedup 1.0000x reference)
//
#include <hip/hip_runtime.h>

typedef __attribute__((ext_vector_type(8))) short short8;
typedef __attribute__((ext_vector_type(4))) short short4v;
typedef __attribute__((ext_vector_type(4))) float float4v;
typedef __attribute__((ext_vector_type(2))) unsigned int uint2v;

#define NDIM 512
#define NN (NDIM*NDIM)
#define CD 128

__device__ __forceinline__ unsigned short f2b(float f) {
  union { float f; unsigned u; } v; v.f = f;
  unsigned r = v.u + 0x7FFFu + ((v.u >> 16) & 1u);
  return (unsigned short)(r >> 16);
}
__device__ __forceinline__ float b2f(unsigned short h) {
  union { unsigned u; float f; } v; v.u = ((unsigned)h) << 16; return v.f;
}
__device__ __forceinline__ float sigmoidf_(float x) { return 1.f / (1.f + __expf(-x)); }
// packed f32x2 -> bf16x2 (RNE), single VALU op
__device__ __forceinline__ unsigned pk2(float a, float b) {
  unsigned r;
  asm("v_cvt_pk_bf16_f32 %0, %1, %2" : "=v"(r) : "v"(a), "v"(b));
  return r;
}
__device__ __forceinline__ float4v mfma16(short8 a, short8 b, float4v c) {
  return __builtin_amdgcn_mfma_f32_16x16x32_bf16(a, b, c, 0, 0, 0);
}
__device__ __forceinline__ void gl_lds16(const short* g, short* l) {
  __builtin_amdgcn_global_load_lds(
      (const __attribute__((address_space(1))) unsigned int*)g,
      (__attribute__((address_space(3))) unsigned int*)l, 16, 0, 0);
}

// fragment read from a swizzled 128-short-row LDS buffer: logical (row, 16B-chunk j)
__device__ __forceinline__ short8 fragr(const short* buf, int row, int j) {
  return *(const short8*)(buf + row * 128 + ((j ^ (row & 15)) << 3));
}

// ---------------- kernel 0: weight prep f32 [k][n] -> bf16 [n][k] ----------------
__global__ __launch_bounds__(256) void kPrepW(
    const float* __restrict__ w0, const float* __restrict__ w1,
    const float* __restrict__ w2, const float* __restrict__ w3,
    const float* __restrict__ w4, short* __restrict__ wt)
{
  const int wi = blockIdx.y;
  const float* W = wi==0 ? w0 : wi==1 ? w1 : wi==2 ? w2 : wi==3 ? w3 : w4;
  const int e = blockIdx.x * 256 + threadIdx.x;   // 0..16383
  const int k = e >> 7, n = e & 127;              // coalesced read along n
  wt[wi * 16384 + n * 128 + k] = (short)f2b(W[k * CD + n]);
}

// ---------------- kernel 1: LN(z) + 5 projections + gating ----------------
// 2048 blocks x 256 thr; block = 128 rows; wave = 32 rows (2 rowgroups)
// Double-buffered weight staging: zln becomes wbuf0 once af is in registers.
__global__ __launch_bounds__(256, 2) void kProj(
    const float* __restrict__ z, const float* __restrict__ mask,
    const short* __restrict__ wT,
    const float* __restrict__ b_a_p, const float* __restrict__ b_a_g,
    const float* __restrict__ b_b_p, const float* __restrict__ b_b_g,
    const float* __restrict__ b_g,
    const float* __restrict__ ln_s, const float* __restrict__ ln_b,
    short* __restrict__ a_t, short* __restrict__ b_t, short* __restrict__ g_out)
{
  __shared__ short zln[128 * 128];   // swizzled; reused as weight buf0 after B2
  __shared__ short sW[128 * 128];    // swizzled weight buf1
  const int t = threadIdx.x;
  const int r0 = blockIdx.x * 128;
  const int w = t >> 6, l = t & 63, lr = l & 15, lg = l >> 4;

  // per-thread staging offsets (same for every weight slot)
  int soff[8], doff[8];
#pragma unroll
  for (int i = 0; i < 8; ++i) {
    int U = i * 256 + t;
    int row = U >> 4, u = U & 15;
    soff[i] = row * 128 + ((u ^ (row & 15)) << 3);
    doff[i] = U * 8;
  }
#define STAGE(BUF, SLOT) do { _Pragma("unroll") for (int i_ = 0; i_ < 8; ++i_) \
    gl_lds16(wT + (SLOT) * 16384 + soff[i_], (BUF) + doff[i_]); } while(0)

  STAGE(sW, 1);                                   // w_a_g -> buf1 (covers LN)

  // ---- LN of 128 rows, 2 rounds, 4 threads/row ----
#pragma unroll
  for (int h = 0; h < 2; ++h) {
    const int row = h * 64 + (t >> 2), q = t & 3;
    const float* zp = z + (size_t)(r0 + row) * CD + q * 32;
    float x[32];
#pragma unroll
    for (int i = 0; i < 8; ++i) {
      float4v v = *(const float4v*)(zp + i * 4);
#pragma unroll
      for (int e = 0; e < 4; ++e) x[i*4+e] = v[e];
    }
    float s = 0.f;
#pragma unroll
    for (int i = 0; i < 32; ++i) s += x[i];
    s += __shfl_xor(s, 1, 64);
    s += __shfl_xor(s, 2, 64);
    const float mu = s * (1.f/128.f);
    float vs = 0.f;
#pragma unroll
    for (int i = 0; i < 32; ++i) { float d = x[i]-mu; vs += d*d; }
    vs += __shfl_xor(vs, 1, 64);
    vs += __shfl_xor(vs, 2, 64);
    const float rstd = rsqrtf(vs * (1.f/128.f) + 1e-5f);
#pragma unroll
    for (int i = 0; i < 32; i += 2) {             // paired bf16 stores
      int c = q*32 + i;
      float y0 = (x[i]  -mu)*rstd*ln_s[c]   + ln_b[c];
      float y1 = (x[i+1]-mu)*rstd*ln_s[c+1] + ln_b[c+1];
      int addr = row*128 + (((c>>3) ^ (row & 15)) << 3) + (c & 7);
      *(unsigned*)(&zln[addr]) = pk2(y0, y1);
    }
  }

  // biases + mask (issue before barrier)
  float bga[8], bpa[8], bgb[8], bpb[8];
#pragma unroll
  for (int cf = 0; cf < 8; ++cf) {
    bga[cf] = b_a_g[cf*16+lr]; bpa[cf] = b_a_p[cf*16+lr];
    bgb[cf] = b_b_g[cf*16+lr]; bpb[cf] = b_b_p[cf*16+lr];
  }
  float mrow[2][4];
#pragma unroll
  for (int g = 0; g < 2; ++g)
#pragma unroll
    for (int jj = 0; jj < 4; ++jj)
      mrow[g][jj] = mask[r0 + w*32 + g*16 + lg*4 + jj];

  __syncthreads();                                // B1: zln + sW(w_a_g) ready

  short8 af[2][4];
#pragma unroll
  for (int g = 0; g < 2; ++g)
#pragma unroll
    for (int ks = 0; ks < 4; ++ks)
      af[g][ks] = fragr(zln, w*32 + g*16 + lr, ks*4 + lg);
  __syncthreads();                                // B2: af in regs -> zln = wbuf0

  float4v accA[2][8], accB[2][8];
  float sg[2][8][4];

#define ZERO_ACC(A) do { _Pragma("unroll") for (int g_=0;g_<2;++g_) \
  _Pragma("unroll") for (int c_=0;c_<8;++c_) A[g_][c_] = (float4v){0.f,0.f,0.f,0.f}; } while(0)

  // pass: acc[g][cf] += af[g][ks] x BUF-frag  (unswapped: D = (rows, c))
#define WPASS(A, BUF) do { ZERO_ACC(A);                                    \
  __builtin_amdgcn_s_setprio(1);                                           \
  _Pragma("unroll") for (int ks_=0; ks_<4; ++ks_)                          \
    _Pragma("unroll") for (int cf_=0; cf_<8; ++cf_) {                      \
      short8 wf_ = fragr(BUF, cf_*16 + lr, ks_*4 + lg);                    \
      _Pragma("unroll") for (int g_=0; g_<2; ++g_)                         \
        A[g_][cf_] = mfma16(af[g_][ks_], wf_, A[g_][cf_]);                 \
    }                                                                      \
  __builtin_amdgcn_s_setprio(0); } while(0)

#define SIGPASS(BG) do { _Pragma("unroll") for (int g_=0;g_<2;++g_)        \
  _Pragma("unroll") for (int cf_=0;cf_<8;++cf_)                            \
    _Pragma("unroll") for (int j_=0;j_<4;++j_)                             \
      sg[g_][cf_][j_] = sigmoidf_(accA[g_][cf_][j_] + BG[cf_]) * mrow[g_][j_]; } while(0)

  // packed 8B store of (sg * (accB + bias)) to DST[c][rows]
#define STORE_AB(DST, BP) do { _Pragma("unroll") for (int g_=0;g_<2;++g_)  \
  _Pragma("unroll") for (int cf_=0;cf_<8;++cf_) {                          \
    float v0_ = sg[g_][cf_][0] * (accB[g_][cf_][0] + BP[cf_]);             \
    float v1_ = sg[g_][cf_][1] * (accB[g_][cf_][1] + BP[cf_]);             \
    float v2_ = sg[g_][cf_][2] * (accB[g_][cf_][2] + BP[cf_]);             \
    float v3_ = sg[g_][cf_][3] * (accB[g_][cf_][3] + BP[cf_]);             \
    uint2v pv_ = { pk2(v0_, v1_), pk2(v2_, v3_) };                         \
    *(uint2v*)(DST + (size_t)(cf_*16+lr)*NN + r0 + w*32 + g_*16 + lg*4) = pv_; \
  } } while(0)

  STAGE(zln, 0);                                  // w_a_p -> buf0
  WPASS(accA, sW);                                // a_g
  __syncthreads();                                // B3: a_p ready; sW reads done
  STAGE(sW, 3);                                   // w_b_g -> buf1
  WPASS(accB, zln);                               // a_p
  SIGPASS(bga);                                   // sg from a_g
  __syncthreads();                                // B4: b_g ready; zln reads done
  STAGE(zln, 2);                                  // w_b_p -> buf0
  WPASS(accA, sW);                                // b_g
  STORE_AB(a_t, bpa);                             // a = sg(a_g) * (a_p + b)
  __syncthreads();                                // B5: b_p ready; sW reads done
  STAGE(sW, 4);                                   // w_g -> buf1
  WPASS(accB, zln);                               // b_p
  SIGPASS(bgb);                                   // sg from b_g
  __syncthreads();                                // B6: w_g ready; zln reads done

  // gate pass, swapped operands: D = (c, rows) -> row-major 8B stores
  {
    float4v accG[2][8];
    ZERO_ACC(accG);
    __builtin_amdgcn_s_setprio(1);
#pragma unroll
    for (int ks = 0; ks < 4; ++ks)
#pragma unroll
      for (int cf = 0; cf < 8; ++cf) {
        short8 wf = fragr(sW, cf*16 + lr, ks*4 + lg);
#pragma unroll
        for (int g = 0; g < 2; ++g)
          accG[g][cf] = mfma16(wf, af[g][ks], accG[g][cf]);
      }
    __builtin_amdgcn_s_setprio(0);
    STORE_AB(b_t, bpb);                           // b = sg(b_g) * (b_p + b)
#pragma unroll
    for (int g = 0; g < 2; ++g)
#pragma unroll
      for (int cf = 0; cf < 8; ++cf) {
        float4v bgv = *(const float4v*)(b_g + cf*16 + lg*4);
        float v0 = sigmoidf_(accG[g][cf][0] + bgv[0]);
        float v1 = sigmoidf_(accG[g][cf][1] + bgv[1]);
        float v2 = sigmoidf_(accG[g][cf][2] + bgv[2]);
        float v3 = sigmoidf_(accG[g][cf][3] + bgv[3]);
        uint2v pv = { pk2(v0, v1), pk2(v2, v3) };
        *(uint2v*)(g_out + (size_t)(r0 + w*32 + g*16 + lr)*CD + cf*16 + lg*4) = pv;
      }
  }
}

// ---------------- kernel 2: per-channel einsum GEMM X_c = A_c * B_c^T ----------------
// BK=64, double-buffered, 2-phase pipeline
__global__ __launch_bounds__(256, 2) void kEinsum(const short* __restrict__ a_t,
                                                  const short* __restrict__ b_t,
                                                  short* __restrict__ x_t)
{
  __shared__ short As[2][128 * 64];
  __shared__ short Bs[2][128 * 64];
  const int t = threadIdx.x;
  const int d = blockIdx.x;
  const int c = (d & 7) * 16 + (d >> 7);          // channel -> XCD grouping
  const int tile = (d >> 3) & 15;
  const int i0 = (tile >> 2) * 128;
  const int j0 = (tile & 3) * 128;
  const size_t abase = (size_t)c * NN;
  const int w = t >> 6, l = t & 63, lr = l & 15, lg = l >> 4;
  const int wr = w >> 1, wc = w & 1;

  // staging source addresses (pre-swizzled global chunks, linear LDS dest)
  const short* gA[4]; const short* gB[4]; int ldsU[4];
#pragma unroll
  for (int q = 0; q < 4; ++q) {
    int U = q * 256 + t;                          // 16B-unit index, 0..1023
    int row = U >> 3, u = U & 7;
    int swz = ((u ^ (row & 7)) << 3);
    gA[q] = a_t + abase + (size_t)(i0 + row) * NDIM + swz;
    gB[q] = b_t + abase + (size_t)(j0 + row) * NDIM + swz;
    ldsU[q] = U * 8;
  }

#define STAGE_E(buf, k0) do { _Pragma("unroll") for (int q_=0;q_<4;++q_) { \
    gl_lds16(gA[q_] + (k0), &As[buf][ldsU[q_]]);                           \
    gl_lds16(gB[q_] + (k0), &Bs[buf][ldsU[q_]]); } } while(0)

  float4v acc[4][4];
#pragma unroll
  for (int m = 0; m < 4; ++m)
#pragma unroll
    for (int n = 0; n < 4; ++n) acc[m][n] = (float4v){0.f,0.f,0.f,0.f};

  STAGE_E(0, 0);
  __syncthreads();                                // prologue drain
  int cur = 0;
#pragma unroll
  for (int it = 0; it < 8; ++it) {
    if (it < 7) STAGE_E(cur ^ 1, (it + 1) * 64);
    short8 afr[4][2], bfr[4][2];
#pragma unroll
    for (int m = 0; m < 4; ++m)
#pragma unroll
      for (int ks = 0; ks < 2; ++ks) {
        int row = wr*64 + m*16 + lr, j = ks*4 + lg;
        afr[m][ks] = *(const short8*)(&As[cur][row*64 + ((j ^ (row & 7)) << 3)]);
      }
#pragma unroll
    for (int n = 0; n < 4; ++n)
#pragma unroll
      for (int ks = 0; ks < 2; ++ks) {
        int row = wc*64 + n*16 + lr, j = ks*4 + lg;
        bfr[n][ks] = *(const short8*)(&Bs[cur][row*64 + ((j ^ (row & 7)) << 3)]);
      }
    __builtin_amdgcn_s_setprio(1);
#pragma unroll
    for (int ks = 0; ks < 2; ++ks)
#pragma unroll
      for (int m = 0; m < 4; ++m)
#pragma unroll
        for (int n = 0; n < 4; ++n)   // swapped: D = (j, i) -> j-major stores
          acc[m][n] = mfma16(bfr[n][ks], afr[m][ks], acc[m][n]);
    __builtin_amdgcn_s_setprio(0);
    __syncthreads();
    cur ^= 1;
  }
  // epilogue: lane holds 4 consecutive j (jj) of one i -> packed 8B stores
#pragma unroll
  for (int m = 0; m < 4; ++m)
#pragma unroll
    for (int n = 0; n < 4; ++n) {
      int i  = i0 + wr*64 + m*16 + lr;
      int jb = j0 + wc*64 + n*16 + lg*4;
      uint2v pv = { pk2(acc[m][n][0], acc[m][n][1]), pk2(acc[m][n][2], acc[m][n][3]) };
      *(uint2v*)(x_t + abase + (size_t)i * NDIM + jb) = pv;
    }
}

// ---------------- kernel 3: LN(x) + x@w_z + b_z, * gate ----------------
__global__ __launch_bounds__(256, 2) void kOut(
    const short* __restrict__ x_t, const short* __restrict__ g_in,
    const float* __restrict__ w_z, const float* __restrict__ b_z,
    const float* __restrict__ ln_s, const float* __restrict__ ln_b,
    float* __restrict__ out)
{
  __shared__ short xs[128 * 72];    // gathered x [c][r], swizzled r-chunks
  __shared__ short xln[64 * 128];   // swizzled
  __shared__ short sW[128 * 128];   // swizzled w_z
  const int t = threadIdx.x;
  const int r0 = blockIdx.x * 64;
  const int w = t >> 6, l = t & 63, lr = l & 15, lg = l >> 4;

  // A) stage w_z f32 [k][n] -> swizzled bf16 [n][k] (coalesced reads, one-time)
#pragma unroll
  for (int i = 0; i < 8; ++i) {
    int flat = i * 256 + t;                       // k-pair unit
    int kp = flat >> 5, k = kp * 2, n4 = (flat & 31) * 4;
    float4v va = *(const float4v*)(w_z + (size_t)k * CD + n4);
    float4v vb = *(const float4v*)(w_z + (size_t)(k + 1) * CD + n4);
#pragma unroll
    for (int j = 0; j < 4; ++j) {
      int row = n4 + j;
      int addr = row * 128 + (((k >> 3) ^ (row & 15)) << 3) + (k & 7);
      *(unsigned*)(&sW[addr]) = pk2(va[j], vb[j]);
    }
  }
  // B) gather x columns -> xs (swizzled 16B chunks)
#pragma unroll
  for (int it = 0; it < 4; ++it) {
    int v = it * 256 + t; int cc = v >> 3; int u = v & 7;
    int up = u ^ ((cc >> 3) & 7);
    *(short8*)&xs[cc * 72 + up * 8] = *(const short8*)(x_t + (size_t)cc * NN + r0 + u * 8);
  }
  __syncthreads();                                // s1
  // C) LN over channels
  {
    const int r = t >> 2, q = t & 3;
    float x[32];
#pragma unroll
    for (int i = 0; i < 32; ++i) {
      int c = q * 32 + i;
      x[i] = b2f((unsigned short)xs[c * 72 + (((r >> 3) ^ ((c >> 3) & 7)) << 3) + (r & 7)]);
    }
    float s = 0.f;
#pragma unroll
    for (int i = 0; i < 32; ++i) s += x[i];
    s += __shfl_xor(s, 1, 64);
    s += __shfl_xor(s, 2, 64);
    const float mu = s * (1.f/128.f);
    float vs = 0.f;
#pragma unroll
    for (int i = 0; i < 32; ++i) { float d = x[i]-mu; vs += d*d; }
    vs += __shfl_xor(vs, 1, 64);
    vs += __shfl_xor(vs, 2, 64);
    const float rstd = rsqrtf(vs * (1.f/128.f) + 1e-5f);
#pragma unroll
    for (int i = 0; i < 32; ++i) {
      int c = q*32 + i;
      float y = (x[i]-mu)*rstd*ln_s[c] + ln_b[c];
      xln[r*128 + (((c>>3) ^ (r & 15)) << 3) + (c & 7)] = (short)f2b(y);
    }
  }
  __syncthreads();                                // s2
  short8 af[4];
#pragma unroll
  for (int ks = 0; ks < 4; ++ks)
    af[ks] = fragr(xln, w*16 + lr, ks*4 + lg);

  // D) swapped final mfma: D = (c, rows) -> coalesced float4 out stores
  float4v acc[8];
#pragma unroll
  for (int cf = 0; cf < 8; ++cf) acc[cf] = (float4v){0.f,0.f,0.f,0.f};
#pragma unroll
  for (int ks = 0; ks < 4; ++ks)
#pragma unroll
    for (int cf = 0; cf < 8; ++cf) {
      short8 wf = fragr(sW, cf*16 + lr, ks*4 + lg);
      acc[cf] = mfma16(wf, af[ks], acc[cf]);
    }
  const int orow = r0 + w*16 + lr;
#pragma unroll
  for (int cf = 0; cf < 8; ++cf) {
    float4v bzv = *(const float4v*)(b_z + cf*16 + lg*4);
    short4v gv = *(const short4v*)(g_in + (size_t)orow * CD + cf*16 + lg*4);
    float4v o;
#pragma unroll
    for (int j = 0; j < 4; ++j)
      o[j] = (acc[cf][j] + bzv[j]) * b2f((unsigned short)gv[j]);
    *(float4v*)(out + (size_t)orow * CD + cf*16 + lg*4) = o;
  }
}

extern "C" void kernel_launch(void* const* d_in, const int* in_sizes, int n_in,
                              void* d_out, int out_size, void* d_ws, size_t ws_size,
                              hipStream_t stream) {
  (void)in_sizes; (void)n_in; (void)out_size; (void)ws_size;
  const float* z     = (const float*)d_in[0];
  const float* mask  = (const float*)d_in[1];
  const float* w_a_p = (const float*)d_in[2];
  const float* b_a_p = (const float*)d_in[3];
  const float* w_a_g = (const float*)d_in[4];
  const float* b_a_g = (const float*)d_in[5];
  const float* w_b_p = (const float*)d_in[6];
  const float* b_b_p = (const float*)d_in[7];
  const float* w_b_g = (const float*)d_in[8];
  const float* b_b_g = (const float*)d_in[9];
  const float* w_g   = (const float*)d_in[10];
  const float* b_g   = (const float*)d_in[11];
  const float* w_z   = (const float*)d_in[12];
  const float* b_z   = (const float*)d_in[13];
  const float* ln_i_s = (const float*)d_in[14];
  const float* ln_i_b = (const float*)d_in[15];
  const float* ln_o_s = (const float*)d_in[16];
  const float* ln_o_b = (const float*)d_in[17];

  short* a_t = (short*)d_ws;                       // 64 MiB each, 256 MiB total
  short* b_t = a_t + (size_t)CD*NN;
  short* g_s = b_t + (size_t)CD*NN;
  short* x_t = g_s + (size_t)CD*NN;
  short* wT  = x_t;                                // 160 KB at head of x_t (kProj only)

  hipLaunchKernelGGL(kPrepW, dim3(64, 5), dim3(256), 0, stream,
                     w_a_p, w_a_g, w_b_p, w_b_g, w_g, wT);
  hipLaunchKernelGGL(kProj, dim3(NN/128), dim3(256), 0, stream,
                     z, mask, wT, b_a_p, b_a_g, b_b_p, b_b_g, b_g,
                     ln_i_s, ln_i_b, a_t, b_t, g_s);
  hipLaunchKernelGGL(kEinsum, dim3(2048), dim3(256), 0, stream, a_t, b_t, x_t);
  hipLaunchKernelGGL(kOut, dim3(NN/64), dim3(256), 0, stream,
                     x_t, g_s, w_z, b_z, ln_o_s, ln_o_b, (float*)d_out);
}

// Round 5
// 347.853 us; speedup vs baseline: 1.0621x; 1.0621x over previous
//
#include <hip/hip_runtime.h>

typedef __attribute__((ext_vector_type(8))) short short8;
typedef __attribute__((ext_vector_type(4))) short short4v;
typedef __attribute__((ext_vector_type(4))) float float4v;

#define NDIM 512
#define NN (NDIM*NDIM)
#define CD 128

__device__ __forceinline__ unsigned short f2b(float f) {
  union { float f; unsigned u; } v; v.f = f;
  unsigned r = v.u + 0x7FFFu + ((v.u >> 16) & 1u);
  return (unsigned short)(r >> 16);
}
__device__ __forceinline__ float b2f(unsigned short h) {
  union { unsigned u; float f; } v; v.u = ((unsigned)h) << 16; return v.f;
}
__device__ __forceinline__ float sigmoidf_(float x) { return 1.f / (1.f + __expf(-x)); }
// packed f32x2 -> bf16x2 (RNE), single VALU op
__device__ __forceinline__ unsigned pk2(float a, float b) {
  unsigned r;
  asm("v_cvt_pk_bf16_f32 %0, %1, %2" : "=v"(r) : "v"(a), "v"(b));
  return r;
}
__device__ __forceinline__ float4v mfma16(short8 a, short8 b, float4v c) {
  return __builtin_amdgcn_mfma_f32_16x16x32_bf16(a, b, c, 0, 0, 0);
}
__device__ __forceinline__ void gl_lds16(const short* g, short* l) {
  __builtin_amdgcn_global_load_lds(
      (const __attribute__((address_space(1))) unsigned int*)g,
      (__attribute__((address_space(3))) unsigned int*)l, 16, 0, 0);
}

// swizzled LDS tile, rows of 128 shorts (16 chunks of 16B), chunk ^= row&15
__device__ __forceinline__ short8 fragr(const short* buf, int row, int j) {
  return *(const short8*)(buf + row * 128 + ((j ^ (row & 15)) << 3));
}
// 4B write into the same swizzled layout: ku = uint-index in [0,64)
__device__ __forceinline__ void stg_w(short* buf, int row, int ku, unsigned v) {
  *(unsigned*)&buf[row * 128 + ((((ku >> 2) ^ (row & 15)) << 3) + ((ku & 3) << 1))] = v;
}

// ---------------- kernel 0: weight prep f32 [k][n] -> bf16 [n][k] ----------------
__global__ __launch_bounds__(256) void kPrepW(
    const float* __restrict__ w0, const float* __restrict__ w1,
    const float* __restrict__ w2, const float* __restrict__ w3,
    const float* __restrict__ w4, short* __restrict__ wt)
{
  const int wi = blockIdx.y;
  const float* W = wi==0 ? w0 : wi==1 ? w1 : wi==2 ? w2 : wi==3 ? w3 : w4;
  const int e = blockIdx.x * 256 + threadIdx.x;   // 0..16383
  const int k = e >> 7, n = e & 127;              // coalesced read along n
  wt[wi * 16384 + n * 128 + k] = (short)f2b(W[k * CD + n]);
}

// ---------------- kernel 1: LN(z) + 5 projections + gating ----------------
// 2048 blocks x 256 thr; block = 128 flat rows; all global stores full-sector
__global__ __launch_bounds__(256, 2) void kProj(
    const float* __restrict__ z, const float* __restrict__ mask,
    const short* __restrict__ wT,
    const float* __restrict__ b_a_p, const float* __restrict__ b_a_g,
    const float* __restrict__ b_b_p, const float* __restrict__ b_b_g,
    const float* __restrict__ b_g,
    const float* __restrict__ ln_s, const float* __restrict__ ln_b,
    short* __restrict__ a_t, short* __restrict__ b_t, short* __restrict__ g_out)
{
  __shared__ short zln[128 * 128];     // swizzled; weight buf0 after B2; bv stage at end
  __shared__ short sW[128 * 128];      // swizzled weight buf1; gv stage at end
  __shared__ short sStage[64 * 128];   // 16KB store-transpose buffer (a halves)
  const int t = threadIdx.x;
  const int r0 = blockIdx.x * 128;
  const int w = t >> 6, l = t & 63, lr = l & 15, lg = l >> 4;

  // per-thread weight staging offsets
  int soff[8], doff[8];
#pragma unroll
  for (int i = 0; i < 8; ++i) {
    int U = i * 256 + t;
    int row = U >> 4, u = U & 15;
    soff[i] = row * 128 + ((u ^ (row & 15)) << 3);
    doff[i] = U * 8;
  }
#define STAGE(BUF, SLOT) do { _Pragma("unroll") for (int i_ = 0; i_ < 8; ++i_) \
    gl_lds16(wT + (SLOT) * 16384 + soff[i_], (BUF) + doff[i_]); } while(0)

  STAGE(sW, 1);                                   // S0: w_a_g (covers LN)

  // ---- LN of 128 rows, 2 rounds, 4 threads/row ----
#pragma unroll
  for (int h = 0; h < 2; ++h) {
    const int row = h * 64 + (t >> 2), q = t & 3;
    const float* zp = z + (size_t)(r0 + row) * CD + q * 32;
    float x[32];
#pragma unroll
    for (int i = 0; i < 8; ++i) {
      float4v v = *(const float4v*)(zp + i * 4);
#pragma unroll
      for (int e = 0; e < 4; ++e) x[i*4+e] = v[e];
    }
    float s = 0.f;
#pragma unroll
    for (int i = 0; i < 32; ++i) s += x[i];
    s += __shfl_xor(s, 1, 64);
    s += __shfl_xor(s, 2, 64);
    const float mu = s * (1.f/128.f);
    float vs = 0.f;
#pragma unroll
    for (int i = 0; i < 32; ++i) { float d = x[i]-mu; vs += d*d; }
    vs += __shfl_xor(vs, 1, 64);
    vs += __shfl_xor(vs, 2, 64);
    const float rstd = rsqrtf(vs * (1.f/128.f) + 1e-5f);
#pragma unroll
    for (int i = 0; i < 32; i += 2) {
      int c = q*32 + i;
      float y0 = (x[i]  -mu)*rstd*ln_s[c]   + ln_b[c];
      float y1 = (x[i+1]-mu)*rstd*ln_s[c+1] + ln_b[c+1];
      int addr = row*128 + (((c>>3) ^ (row & 15)) << 3) + (c & 7);
      *(unsigned*)(&zln[addr]) = pk2(y0, y1);
    }
  }

  float bga[8], bpa[8], bgb[8], bpb[8];
#pragma unroll
  for (int cf = 0; cf < 8; ++cf) {
    bga[cf] = b_a_g[cf*16+lr]; bpa[cf] = b_a_p[cf*16+lr];
    bgb[cf] = b_b_g[cf*16+lr]; bpb[cf] = b_b_p[cf*16+lr];
  }
  float mrow[2][4];
#pragma unroll
  for (int g = 0; g < 2; ++g)
#pragma unroll
    for (int jj = 0; jj < 4; ++jj)
      mrow[g][jj] = mask[r0 + w*32 + g*16 + lg*4 + jj];

  __syncthreads();                                // B1: zln + sW(w_a_g)

  short8 af[2][4];
#pragma unroll
  for (int g = 0; g < 2; ++g)
#pragma unroll
    for (int ks = 0; ks < 4; ++ks)
      af[g][ks] = fragr(zln, w*32 + g*16 + lr, ks*4 + lg);
  __syncthreads();                                // B2: zln free

  float4v accG[2][8], accB[2][8];
  float sg[2][8][4];
  unsigned avh2[16], bvp[32];

#define ZERO_ACC(A) do { _Pragma("unroll") for (int g_=0;g_<2;++g_) \
  _Pragma("unroll") for (int c_=0;c_<8;++c_) A[g_][c_] = (float4v){0.f,0.f,0.f,0.f}; } while(0)

#define WPASS(A, BUF) do { ZERO_ACC(A);                                    \
  __builtin_amdgcn_s_setprio(1);                                           \
  _Pragma("unroll") for (int ks_=0; ks_<4; ++ks_)                          \
    _Pragma("unroll") for (int cf_=0; cf_<8; ++cf_) {                      \
      short8 wf_ = fragr(BUF, cf_*16 + lr, ks_*4 + lg);                    \
      _Pragma("unroll") for (int g_=0; g_<2; ++g_)                         \
        A[g_][cf_] = mfma16(af[g_][ks_], wf_, A[g_][cf_]);                 \
    }                                                                      \
  __builtin_amdgcn_s_setprio(0); } while(0)

#define SIGPASS(BG) do { _Pragma("unroll") for (int g_=0;g_<2;++g_)        \
  _Pragma("unroll") for (int cf_=0;cf_<8;++cf_)                            \
    _Pragma("unroll") for (int j_=0;j_<4;++j_)                             \
      sg[g_][cf_][j_] = sigmoidf_(accG[g_][cf_][j_] + BG[cf_]) * mrow[g_][j_]; } while(0)

  // S2
  STAGE(zln, 0);                                  // w_a_p -> buf0
  WPASS(accG, sW);                                // a_g
  SIGPASS(bga);
  __syncthreads();                                // B3
  // S3
  STAGE(sW, 3);                                   // w_b_g -> buf1
  WPASS(accB, zln);                               // a_p
#pragma unroll
  for (int g = 0; g < 2; ++g)
#pragma unroll
    for (int cf = 0; cf < 8; ++cf) {
      float v0 = sg[g][cf][0]*(accB[g][cf][0]+bpa[cf]);
      float v1 = sg[g][cf][1]*(accB[g][cf][1]+bpa[cf]);
      float v2 = sg[g][cf][2]*(accB[g][cf][2]+bpa[cf]);
      float v3 = sg[g][cf][3]*(accB[g][cf][3]+bpa[cf]);
      unsigned p0 = pk2(v0,v1), p1 = pk2(v2,v3);
      int ku = w*16 + g*8 + lg*2;
      if (cf < 4) { stg_w(sStage, cf*16+lr, ku, p0); stg_w(sStage, cf*16+lr, ku+1, p1); }
      else { avh2[g*8+(cf-4)*2] = p0; avh2[g*8+(cf-4)*2+1] = p1; }
    }
  __syncthreads();                                // B4
  // S4
  STAGE(zln, 2);                                  // w_b_p -> buf0
  WPASS(accG, sW);                                // b_g
  SIGPASS(bgb);
#pragma unroll
  for (int i = 0; i < 4; ++i) {                   // store a half1 (full sectors)
    int ch = t >> 2, cL = (t & 3)*4 + i;
    *(short8*)(a_t + (size_t)ch*NN + r0 + cL*8) = fragr(sStage, ch, cL);
  }
  __syncthreads();                                // B5
  // S5
  STAGE(sW, 4);                                   // w_g -> buf1
#pragma unroll
  for (int g = 0; g < 2; ++g)                     // write a half2 -> sStage
#pragma unroll
    for (int cf = 0; cf < 4; ++cf) {
      int ku = w*16 + g*8 + lg*2;
      stg_w(sStage, cf*16+lr, ku,   avh2[g*8+cf*2]);
      stg_w(sStage, cf*16+lr, ku+1, avh2[g*8+cf*2+1]);
    }
  WPASS(accB, zln);                               // b_p
#pragma unroll
  for (int g = 0; g < 2; ++g)                     // bv packed to regs
#pragma unroll
    for (int cf = 0; cf < 8; ++cf) {
      float v0 = sg[g][cf][0]*(accB[g][cf][0]+bpb[cf]);
      float v1 = sg[g][cf][1]*(accB[g][cf][1]+bpb[cf]);
      float v2 = sg[g][cf][2]*(accB[g][cf][2]+bpb[cf]);
      float v3 = sg[g][cf][3]*(accB[g][cf][3]+bpb[cf]);
      bvp[g*16+cf*2]   = pk2(v0,v1);
      bvp[g*16+cf*2+1] = pk2(v2,v3);
    }
  __syncthreads();                                // B6
  // S6: gate pass (swapped operands: D = (channel, row))
  float4v accG2[2][8];
  ZERO_ACC(accG2);
  __builtin_amdgcn_s_setprio(1);
#pragma unroll
  for (int ks = 0; ks < 4; ++ks)
#pragma unroll
    for (int cf = 0; cf < 8; ++cf) {
      short8 wf = fragr(sW, cf*16 + lr, ks*4 + lg);
#pragma unroll
      for (int g = 0; g < 2; ++g)
        accG2[g][cf] = mfma16(wf, af[g][ks], accG2[g][cf]);
    }
  __builtin_amdgcn_s_setprio(0);
#pragma unroll
  for (int i = 0; i < 4; ++i) {                   // store a half2
    int ch = t >> 2, cL = (t & 3)*4 + i;
    *(short8*)(a_t + (size_t)(64 + ch)*NN + r0 + cL*8) = fragr(sStage, ch, cL);
  }
  __syncthreads();                                // B7: zln,sW free
  // S7: stage bv -> zln (full), gv -> sW (full)
#pragma unroll
  for (int g = 0; g < 2; ++g)
#pragma unroll
    for (int cf = 0; cf < 8; ++cf) {
      int ku = w*16 + g*8 + lg*2;
      stg_w(zln, cf*16+lr, ku,   bvp[g*16+cf*2]);
      stg_w(zln, cf*16+lr, ku+1, bvp[g*16+cf*2+1]);
    }
#pragma unroll
  for (int g = 0; g < 2; ++g)
#pragma unroll
    for (int cf = 0; cf < 8; ++cf) {
      float4v bgv = *(const float4v*)(b_g + cf*16 + lg*4);
      float v0 = sigmoidf_(accG2[g][cf][0] + bgv[0]);
      float v1 = sigmoidf_(accG2[g][cf][1] + bgv[1]);
      float v2 = sigmoidf_(accG2[g][cf][2] + bgv[2]);
      float v3 = sigmoidf_(accG2[g][cf][3] + bgv[3]);
      int row = w*32 + g*16 + lr, ku = cf*8 + lg*2;
      stg_w(sW, row, ku,   pk2(v0,v1));
      stg_w(sW, row, ku+1, pk2(v2,v3));
    }
  __syncthreads();                                // B8
  // S8: full-sector stores of b and g (128B/thread)
#pragma unroll
  for (int i = 0; i < 8; ++i) {
    int ch = t >> 1, cL = (t & 1)*8 + i;
    *(short8*)(b_t + (size_t)ch*NN + r0 + cL*8) = fragr(zln, ch, cL);
  }
#pragma unroll
  for (int i = 0; i < 8; ++i) {
    int row = t >> 1, cL = (t & 1)*8 + i;
    *(short8*)(g_out + (size_t)(r0 + row)*CD + cL*8) = fragr(sW, row, cL);
  }
}

// ---------------- kernel 2: per-channel einsum GEMM X_c = A_c * B_c^T ----------------
__global__ __launch_bounds__(256, 2) void kEinsum(const short* __restrict__ a_t,
                                                  const short* __restrict__ b_t,
                                                  short* __restrict__ x_t)
{
  __shared__ short As[2][128 * 64];
  __shared__ short Bs[2][128 * 64];
  const int t = threadIdx.x;
  const int d = blockIdx.x;
  const int c = (d & 7) * 16 + (d >> 7);          // channel -> XCD grouping
  const int tile = (d >> 3) & 15;
  const int i0 = (tile >> 2) * 128;
  const int j0 = (tile & 3) * 128;
  const size_t abase = (size_t)c * NN;
  const int w = t >> 6, l = t & 63, lr = l & 15, lg = l >> 4;
  const int wr = w >> 1, wc = w & 1;

  const short* gA[4]; const short* gB[4]; int ldsU[4];
#pragma unroll
  for (int q = 0; q < 4; ++q) {
    int U = q * 256 + t;
    int row = U >> 3, u = U & 7;
    int swz = ((u ^ (row & 7)) << 3);
    gA[q] = a_t + abase + (size_t)(i0 + row) * NDIM + swz;
    gB[q] = b_t + abase + (size_t)(j0 + row) * NDIM + swz;
    ldsU[q] = U * 8;
  }

#define STAGE_E(buf, k0) do { _Pragma("unroll") for (int q_=0;q_<4;++q_) { \
    gl_lds16(gA[q_] + (k0), &As[buf][ldsU[q_]]);                           \
    gl_lds16(gB[q_] + (k0), &Bs[buf][ldsU[q_]]); } } while(0)

  float4v acc[4][4];
#pragma unroll
  for (int m = 0; m < 4; ++m)
#pragma unroll
    for (int n = 0; n < 4; ++n) acc[m][n] = (float4v){0.f,0.f,0.f,0.f};

  STAGE_E(0, 0);
  __syncthreads();
  int cur = 0;
#pragma unroll
  for (int it = 0; it < 8; ++it) {
    if (it < 7) STAGE_E(cur ^ 1, (it + 1) * 64);
    short8 afr[4][2], bfr[4][2];
#pragma unroll
    for (int m = 0; m < 4; ++m)
#pragma unroll
      for (int ks = 0; ks < 2; ++ks) {
        int row = wr*64 + m*16 + lr, j = ks*4 + lg;
        afr[m][ks] = *(const short8*)(&As[cur][row*64 + ((j ^ (row & 7)) << 3)]);
      }
#pragma unroll
    for (int n = 0; n < 4; ++n)
#pragma unroll
      for (int ks = 0; ks < 2; ++ks) {
        int row = wc*64 + n*16 + lr, j = ks*4 + lg;
        bfr[n][ks] = *(const short8*)(&Bs[cur][row*64 + ((j ^ (row & 7)) << 3)]);
      }
    __builtin_amdgcn_s_setprio(1);
#pragma unroll
    for (int ks = 0; ks < 2; ++ks)
#pragma unroll
      for (int m = 0; m < 4; ++m)
#pragma unroll
        for (int n = 0; n < 4; ++n)   // swapped: D = (j, i)
          acc[m][n] = mfma16(bfr[n][ks], afr[m][ks], acc[m][n]);
    __builtin_amdgcn_s_setprio(0);
    __syncthreads();
    cur ^= 1;
  }
  // epilogue: stage x-tile into As region (swizzled), then 128B/thread stores
  short* Xs = &As[0][0];                          // 128 x 128 shorts = 32KB
#pragma unroll
  for (int m = 0; m < 4; ++m)
#pragma unroll
    for (int n = 0; n < 4; ++n) {
      int il = wr*64 + m*16 + lr;
      int ku = wc*32 + n*8 + lg*2;
      stg_w(Xs, il, ku,   pk2(acc[m][n][0], acc[m][n][1]));
      stg_w(Xs, il, ku+1, pk2(acc[m][n][2], acc[m][n][3]));
    }
  __syncthreads();
#pragma unroll
  for (int i = 0; i < 8; ++i) {
    int il = t >> 1, cL = (t & 1)*8 + i;
    *(short8*)(x_t + abase + (size_t)(i0 + il)*NDIM + j0 + cL*8) = fragr(Xs, il, cL);
  }
}

// ---------------- kernel 3: LN(x) + x@w_z + b_z, * gate ----------------
__global__ __launch_bounds__(256, 2) void kOut(
    const short* __restrict__ x_t, const short* __restrict__ g_in,
    const float* __restrict__ w_z, const float* __restrict__ b_z,
    const float* __restrict__ ln_s, const float* __restrict__ ln_b,
    float* __restrict__ out)
{
  __shared__ short xs[128 * 72];    // gathered x [c][r], swizzled r-chunks
  __shared__ short xln[64 * 128];   // swizzled
  __shared__ short sW[128 * 128];   // swizzled w_z; f32 out-stage at end
  const int t = threadIdx.x;
  const int r0 = blockIdx.x * 64;
  const int w = t >> 6, l = t & 63, lr = l & 15, lg = l >> 4;

  // A) stage w_z f32 [k][n] -> swizzled bf16 [n][k]
#pragma unroll
  for (int i = 0; i < 8; ++i) {
    int flat = i * 256 + t;
    int kp = flat >> 5, k = kp * 2, n4 = (flat & 31) * 4;
    float4v va = *(const float4v*)(w_z + (size_t)k * CD + n4);
    float4v vb = *(const float4v*)(w_z + (size_t)(k + 1) * CD + n4);
#pragma unroll
    for (int j = 0; j < 4; ++j) {
      int row = n4 + j;
      int addr = row * 128 + (((k >> 3) ^ (row & 15)) << 3) + (k & 7);
      *(unsigned*)(&sW[addr]) = pk2(va[j], vb[j]);
    }
  }
  // B) gather x columns -> xs
#pragma unroll
  for (int it = 0; it < 4; ++it) {
    int v = it * 256 + t; int cc = v >> 3; int u = v & 7;
    int up = u ^ ((cc >> 3) & 7);
    *(short8*)&xs[cc * 72 + up * 8] = *(const short8*)(x_t + (size_t)cc * NN + r0 + u * 8);
  }
  __syncthreads();                                // s1
  // C) LN over channels
  {
    const int r = t >> 2, q = t & 3;
    float x[32];
#pragma unroll
    for (int i = 0; i < 32; ++i) {
      int c = q * 32 + i;
      x[i] = b2f((unsigned short)xs[c * 72 + (((r >> 3) ^ ((c >> 3) & 7)) << 3) + (r & 7)]);
    }
    float s = 0.f;
#pragma unroll
    for (int i = 0; i < 32; ++i) s += x[i];
    s += __shfl_xor(s, 1, 64);
    s += __shfl_xor(s, 2, 64);
    const float mu = s * (1.f/128.f);
    float vs = 0.f;
#pragma unroll
    for (int i = 0; i < 32; ++i) { float d = x[i]-mu; vs += d*d; }
    vs += __shfl_xor(vs, 1, 64);
    vs += __shfl_xor(vs, 2, 64);
    const float rstd = rsqrtf(vs * (1.f/128.f) + 1e-5f);
#pragma unroll
    for (int i = 0; i < 32; ++i) {
      int c = q*32 + i;
      float y = (x[i]-mu)*rstd*ln_s[c] + ln_b[c];
      xln[r*128 + (((c>>3) ^ (r & 15)) << 3) + (c & 7)] = (short)f2b(y);
    }
  }
  __syncthreads();                                // s2
  short8 af[4];
#pragma unroll
  for (int ks = 0; ks < 4; ++ks)
    af[ks] = fragr(xln, w*16 + lr, ks*4 + lg);

  // D) swapped final mfma: D = (channel, row)
  float4v acc[8];
#pragma unroll
  for (int cf = 0; cf < 8; ++cf) acc[cf] = (float4v){0.f,0.f,0.f,0.f};
#pragma unroll
  for (int ks = 0; ks < 4; ++ks)
#pragma unroll
    for (int cf = 0; cf < 8; ++cf) {
      short8 wf = fragr(sW, cf*16 + lr, ks*4 + lg);
      acc[cf] = mfma16(wf, af[ks], acc[cf]);
    }
  __syncthreads();                                // s3: sW reads done -> reuse as f32 stage
  float* fWs = (float*)sW;                        // [64 rows][128 c] f32, chunk-swizzled
  const int orow = r0 + w*16 + lr;
  const int rl = w*16 + lr;
#pragma unroll
  for (int cf = 0; cf < 8; ++cf) {
    float4v bzv = *(const float4v*)(b_z + cf*16 + lg*4);
    short4v gv = *(const short4v*)(g_in + (size_t)orow * CD + cf*16 + lg*4);
    float4v o;
#pragma unroll
    for (int j = 0; j < 4; ++j)
      o[j] = (acc[cf][j] + bzv[j]) * b2f((unsigned short)gv[j]);
    *(float4v*)&fWs[rl*128 + (((cf*4+lg) ^ (rl & 15)) << 2)] = o;
  }
  __syncthreads();                                // s4
#pragma unroll
  for (int i = 0; i < 8; ++i) {                   // 512B contiguous per row
    int row = t >> 2, cL = (t & 3)*8 + i;
    *(float4v*)(out + (size_t)(r0 + row)*CD + cL*4) =
        *(const float4v*)&fWs[row*128 + ((cL ^ (row & 15)) << 2)];
  }
}

extern "C" void kernel_launch(void* const* d_in, const int* in_sizes, int n_in,
                              void* d_out, int out_size, void* d_ws, size_t ws_size,
                              hipStream_t stream) {
  (void)in_sizes; (void)n_in; (void)out_size; (void)ws_size;
  const float* z     = (const float*)d_in[0];
  const float* mask  = (const float*)d_in[1];
  const float* w_a_p = (const float*)d_in[2];
  const float* b_a_p = (const float*)d_in[3];
  const float* w_a_g = (const float*)d_in[4];
  const float* b_a_g = (const float*)d_in[5];
  const float* w_b_p = (const float*)d_in[6];
  const float* b_b_p = (const float*)d_in[7];
  const float* w_b_g = (const float*)d_in[8];
  const float* b_b_g = (const float*)d_in[9];
  const float* w_g   = (const float*)d_in[10];
  const float* b_g   = (const float*)d_in[11];
  const float* w_z   = (const float*)d_in[12];
  const float* b_z   = (const float*)d_in[13];
  const float* ln_i_s = (const float*)d_in[14];
  const float* ln_i_b = (const float*)d_in[15];
  const float* ln_o_s = (const float*)d_in[16];
  const float* ln_o_b = (const float*)d_in[17];

  short* a_t = (short*)d_ws;
  short* b_t = a_t + (size_t)CD*NN;
  short* g_s = b_t + (size_t)CD*NN;
  short* x_t = g_s + (size_t)CD*NN;
  short* wT  = x_t;                                // 160 KB at head of x_t (kProj only)

  hipLaunchKernelGGL(kPrepW, dim3(64, 5), dim3(256), 0, stream,
                     w_a_p, w_a_g, w_b_p, w_b_g, w_g, wT);
  hipLaunchKernelGGL(kProj, dim3(NN/128), dim3(256), 0, stream,
                     z, mask, wT, b_a_p, b_a_g, b_b_p, b_b_g, b_g,
                     ln_i_s, ln_i_b, a_t, b_t, g_s);
  hipLaunchKernelGGL(kEinsum, dim3(2048), dim3(256), 0, stream, a_t, b_t, x_t);
  hipLaunchKernelGGL(kOut, dim3(NN/64), dim3(256), 0, stream,
                     x_t, g_s, w_z, b_z, ln_o_s, ln_o_b, (float*)d_out);
}